// Round 15
// baseline (168.828 us; speedup 1.0000x reference)
//
#include <hip/hip_runtime.h>
#include <hip/hip_bf16.h>
#include <math.h>

constexpr int N_   = 8192;
constexpr int D_   = 256;
constexpr int E_   = 131072;
constexpr int G_   = 16;
constexpr int MN_  = 512;
constexpr int H_   = 8;
constexpr int MAXG_= 512;

typedef __attribute__((ext_vector_type(8))) short short8v;      // 8 bf16 (4 VGPR)
typedef _Float16 half8v __attribute__((ext_vector_type(8)));    // 8 fp16 (4 VGPR)
typedef __attribute__((ext_vector_type(4))) float f32x4;        // MFMA C/D

// ---- bf16 helpers (RTNE via integer ops; inputs finite) ----
__device__ inline ushort f2bf(float f) {
    unsigned u = __float_as_uint(f);
    return (ushort)((u + 0x7FFFu + ((u >> 16) & 1u)) >> 16);
}
__device__ inline float bf2f(ushort h) { return __uint_as_float((unsigned)h << 16); }
// ---- fp16 helpers ----
__device__ inline ushort f2h(float f) {
    _Float16 h = (_Float16)f; ushort u; __builtin_memcpy(&u, &h, 2); return u;
}
__device__ inline unsigned pack_h2(float a, float b) {   // low = a, high = b (RTZ, 1 instr)
    auto h = __builtin_amdgcn_cvt_pkrtz(a, b);
    unsigned u; __builtin_memcpy(&u, &h, 4); return u;
}

// ---------------- prep0: zero deg + init bstart ----------------
__global__ void k_prep0(int* __restrict__ deg, int* __restrict__ bstart) {
    int i = blockIdx.x * 256 + threadIdx.x;
    if (i < N_) deg[i] = 0;
    if (i < G_) bstart[i] = -1;
}

// ---------------- weight transpose + hi/lo split (device helper) ----------------
__device__ void wt_dev(const float* __restrict__ W, int ncols,
                       ushort* __restrict__ wth, ushort* __restrict__ wtl,
                       int bx, int by) {
    __shared__ float tile[32][33];
    int c0 = bx * 32, k0 = by * 32;
    int t = threadIdx.x;
    int tr = t >> 5, tc = t & 31;
#pragma unroll
    for (int i = 0; i < 4; ++i)
        tile[tr * 4 + i][tc] = W[(size_t)(k0 + tr * 4 + i) * ncols + c0 + tc];
    __syncthreads();
    int cr = t >> 3, kq = (t & 7) * 4;
    ushort4 hh, ll;
    float v;
    v = tile[kq + 0][cr]; hh.x = f2bf(v); ll.x = f2bf(v - bf2f(hh.x));
    v = tile[kq + 1][cr]; hh.y = f2bf(v); ll.y = f2bf(v - bf2f(hh.y));
    v = tile[kq + 2][cr]; hh.z = f2bf(v); ll.z = f2bf(v - bf2f(hh.z));
    v = tile[kq + 3][cr]; hh.w = f2bf(v); ll.w = f2bf(v - bf2f(hh.w));
    *(ushort4*)(wth + (size_t)(c0 + cr) * 256 + k0 + kq) = hh;
    *(ushort4*)(wtl + (size_t)(c0 + cr) * 256 + k0 + kq) = ll;
}

// ---------------- prep1: deg atomics + batch bounds + 3 weight transposes ----------------
__global__ __launch_bounds__(256) void k_prep1(
    const int* __restrict__ src, int* __restrict__ deg,
    const int* __restrict__ batch, int* __restrict__ bstart,
    const float* __restrict__ Wq, const float* __restrict__ Wkv,
    const float* __restrict__ Wo,
    ushort* __restrict__ wt_h, ushort* __restrict__ wt_l,
    ushort* __restrict__ wot_h, ushort* __restrict__ wot_l) {
    int bid = blockIdx.x;
    if (bid < 512) {
        int e = bid * 256 + threadIdx.x;
        atomicAdd(deg + src[e], 1);
    } else if (bid < 544) {
        int n = (bid - 512) * 256 + threadIdx.x;
        int g = batch[n];
        if (n == 0 || batch[n - 1] != g) bstart[g] = n;
    } else {
        int wid = bid - 544;
        if (wid < 64)        wt_dev(Wq,  256, wt_h, wt_l, wid & 7, wid >> 3);
        else if (wid < 192)  wt_dev(Wkv, 512, wt_h + 256 * 256, wt_l + 256 * 256,
                                    (wid - 64) & 15, (wid - 64) >> 4);
        else                 wt_dev(Wo,  256, wot_h, wot_l, (wid - 192) & 7, (wid - 192) >> 3);
    }
}

// ---------------- prep2: starts/counts backward-fill + exclusive deg scan ----------------
__global__ void k_prep2(const int* __restrict__ bstart, int* __restrict__ starts,
                        int* __restrict__ counts, const int* __restrict__ deg,
                        int* __restrict__ offs, int* __restrict__ cursor) {
    int t = threadIdx.x;
    if (t == 0) {
        int next = N_;
        for (int g = G_ - 1; g >= 0; --g) {
            int b = bstart[g];
            int s = (b >= 0) ? b : next;
            starts[g] = s;
            counts[g] = next - s;
            next = s;
        }
    }
    __shared__ int sums[256];
    int base = t * 32;
    int local[32];
    int s = 0;
#pragma unroll
    for (int k = 0; k < 32; ++k) { local[k] = deg[base + k]; s += local[k]; }
    sums[t] = s;
    __syncthreads();
    for (int off = 1; off < 256; off <<= 1) {
        int v = (t >= off) ? sums[t - off] : 0;
        __syncthreads();
        sums[t] += v;
        __syncthreads();
    }
    int acc = sums[t] - s;
#pragma unroll
    for (int k = 0; k < 32; ++k) {
        offs[base + k] = acc;
        cursor[base + k] = acc;
        acc += local[k];
    }
}

__global__ void k_fill_csr(const int* __restrict__ src, int* __restrict__ cursor,
                           int* __restrict__ eids) {
    int e = blockIdx.x * 256 + threadIdx.x;
    if (e < E_) {
        int slot = atomicAdd(cursor + src[e], 1);
        eids[slot] = e;
    }
}

// ---------------- dist -> clipped ushort buffer (L2-resident per graph) ----------------
__global__ void k_dist16(const int* __restrict__ dist, ushort* __restrict__ dbuf) {
    size_t i = ((size_t)blockIdx.x * 256 + threadIdx.x) * 8;
    int4 a = *(const int4*)(dist + i);
    int4 b = *(const int4*)(dist + i + 4);
    ushort4 s0, s1;
    s0.x = (ushort)min(a.x, 511); s0.y = (ushort)min(a.y, 511);
    s0.z = (ushort)min(a.z, 511); s0.w = (ushort)min(a.w, 511);
    s1.x = (ushort)min(b.x, 511); s1.y = (ushort)min(b.y, 511);
    s1.z = (ushort)min(b.z, 511); s1.w = (ushort)min(b.w, 511);
    *(ushort4*)(dbuf + i)     = s0;
    *(ushort4*)(dbuf + i + 4) = s1;
}

// ---------------- build dense batch (CSR gather, 4-way unrolled), emit bf16 hi/lo ----------------
__global__ void k_build_dense(const float* __restrict__ nf, const float* __restrict__ cent,
                              const float* __restrict__ ef, const int* __restrict__ deg,
                              const int* __restrict__ offs, const int* __restrict__ eids,
                              const int* __restrict__ batch, const int* __restrict__ starts,
                              ushort* __restrict__ xh, ushort* __restrict__ xl) {
    int t  = blockIdx.x * 256 + threadIdx.x;
    int n  = t >> 6;
    int c4 = (t & 63) * 4;
    if (n >= N_) return;
    int g = batch[n];
    int p = n - starts[g];
    if (p >= MN_) return;
    int row = g * MN_ + p;
    int dn = deg[n];
    int dg = min(dn, MAXG_ - 1);
    float4 a = *(const float4*)(nf   + (size_t)n  * D_ + c4);
    float4 b = *(const float4*)(cent + (size_t)dg * D_ + c4);
    float4 o;
    o.x = a.x + b.x; o.y = a.y + b.y; o.z = a.z + b.z; o.w = a.w + b.w;
    int beg = offs[n], end = beg + dn;
    int idx = beg;
    for (; idx + 4 <= end; idx += 4) {
        int e0 = eids[idx], e1 = eids[idx + 1], e2 = eids[idx + 2], e3 = eids[idx + 3];
        float4 v0 = *(const float4*)(ef + (size_t)e0 * D_ + c4);
        float4 v1 = *(const float4*)(ef + (size_t)e1 * D_ + c4);
        float4 v2 = *(const float4*)(ef + (size_t)e2 * D_ + c4);
        float4 v3 = *(const float4*)(ef + (size_t)e3 * D_ + c4);
        o.x += v0.x; o.y += v0.y; o.z += v0.z; o.w += v0.w;
        o.x += v1.x; o.y += v1.y; o.z += v1.z; o.w += v1.w;
        o.x += v2.x; o.y += v2.y; o.z += v2.z; o.w += v2.w;
        o.x += v3.x; o.y += v3.y; o.z += v3.z; o.w += v3.w;
    }
    for (; idx < end; ++idx) {
        int e = eids[idx];
        float4 v = *(const float4*)(ef + (size_t)e * D_ + c4);
        o.x += v.x; o.y += v.y; o.z += v.z; o.w += v.w;
    }
    ushort4 hh, ll;
    hh.x = f2bf(o.x); ll.x = f2bf(o.x - bf2f(hh.x));
    hh.y = f2bf(o.y); ll.y = f2bf(o.y - bf2f(hh.y));
    hh.z = f2bf(o.z); ll.z = f2bf(o.z - bf2f(hh.z));
    hh.w = f2bf(o.w); ll.w = f2bf(o.w - bf2f(hh.w));
    *(ushort4*)(xh + (size_t)row * D_ + c4) = hh;
    *(ushort4*)(xl + (size_t)row * D_ + c4) = ll;
}

// ---------------- MFMA QKV GEMM: 2 row-tiles/wave; V emitted as fp16 ----------------
__global__ __launch_bounds__(256) void k_gemm_qkv(
    const ushort* __restrict__ xh, const ushort* __restrict__ xl,
    const ushort* __restrict__ wth, const ushort* __restrict__ wtl,
    ushort* __restrict__ qh, ushort* __restrict__ qlo,
    ushort* __restrict__ kh, ushort* __restrict__ klo,
    ushort* __restrict__ vt) {
    int w = threadIdx.x >> 6, lane = threadIdx.x & 63;
    int l15 = lane & 15, quad = lane >> 4;
    int m0 = blockIdx.x * 128 + w * 32;
    int nc0 = blockIdx.y * 64;
    f32x4 acc[2][4] = {};
    const ushort* a0h = xh + (size_t)(m0 + l15) * 256 + quad * 8;
    const ushort* a0l = xl + (size_t)(m0 + l15) * 256 + quad * 8;
    for (int kc = 0; kc < 256; kc += 32) {
        short8v ah0 = *(const short8v*)(a0h + kc);
        short8v al0 = *(const short8v*)(a0l + kc);
        short8v ah1 = *(const short8v*)(a0h + 16 * 256 + kc);
        short8v al1 = *(const short8v*)(a0l + 16 * 256 + kc);
#pragma unroll
        for (int c = 0; c < 4; ++c) {
            size_t bo = (size_t)(nc0 + c * 16 + l15) * 256 + kc + quad * 8;
            short8v bh = *(const short8v*)(wth + bo);
            short8v bl = *(const short8v*)(wtl + bo);
            acc[0][c] = __builtin_amdgcn_mfma_f32_16x16x32_bf16(al0, bh, acc[0][c], 0, 0, 0);
            acc[0][c] = __builtin_amdgcn_mfma_f32_16x16x32_bf16(ah0, bl, acc[0][c], 0, 0, 0);
            acc[0][c] = __builtin_amdgcn_mfma_f32_16x16x32_bf16(ah0, bh, acc[0][c], 0, 0, 0);
            acc[1][c] = __builtin_amdgcn_mfma_f32_16x16x32_bf16(al1, bh, acc[1][c], 0, 0, 0);
            acc[1][c] = __builtin_amdgcn_mfma_f32_16x16x32_bf16(ah1, bl, acc[1][c], 0, 0, 0);
            acc[1][c] = __builtin_amdgcn_mfma_f32_16x16x32_bf16(ah1, bh, acc[1][c], 0, 0, 0);
        }
    }
    int seg = nc0 >> 8;          // 0:Q 1:K 2:V
#pragma unroll
    for (int t = 0; t < 2; ++t) {
        int m0t = m0 + t * 16;
        int g = m0t >> 9;
        int r0 = m0t + quad * 4;
#pragma unroll
        for (int c = 0; c < 4; ++c) {
            int col = nc0 + c * 16 + l15;
            if (seg == 0) {
#pragma unroll
                for (int r = 0; r < 4; ++r) {
                    float v = acc[t][c][r];
                    ushort hh = f2bf(v);
                    qh [(size_t)(r0 + r) * 256 + col] = hh;
                    qlo[(size_t)(r0 + r) * 256 + col] = f2bf(v - bf2f(hh));
                }
            } else if (seg == 1) {
                int cc = col - 256;
#pragma unroll
                for (int r = 0; r < 4; ++r) {
                    float v = acc[t][c][r];
                    ushort hh = f2bf(v);
                    kh [(size_t)(r0 + r) * 256 + cc] = hh;
                    klo[(size_t)(r0 + r) * 256 + cc] = f2bf(v - bf2f(hh));
                }
            } else {
                int cv = col - 512;
                int h = cv >> 5, d = cv & 31;
                int j0 = (m0t & 511) + quad * 4;
                ushort4 vv;
                vv.x = f2h(acc[t][c][0]); vv.y = f2h(acc[t][c][1]);
                vv.z = f2h(acc[t][c][2]); vv.w = f2h(acc[t][c][3]);
                *(ushort4*)(vt + ((size_t)((g * 8 + h) * 32 + d)) * 512 + j0) = vv;
            }
        }
    }
}

// ---------------- attention v2: j-split flash with in-block merge ----------------
// Block: 256 thr = 4 waves = {2 i-pairs} x {2 j-halves}; 1 head, 64 rows per block.
// Grid 1024 -> 4 blocks/CU: 16 waves/CU, depth-8 chains (vs 2 waves/SIMD depth-16).
__global__ __launch_bounds__(256) void k_attn2(
    const ushort* __restrict__ qh, const ushort* __restrict__ qlo,
    const ushort* __restrict__ kh, const ushort* __restrict__ klo,
    const ushort* __restrict__ vt, const ushort* __restrict__ dbuf,
    const float* __restrict__ dist_bias, const int* __restrict__ counts,
    ushort* __restrict__ oh_g, ushort* __restrict__ ol_g)
{
    __shared__ float bias_lds[512];
    __shared__ float ml_lds[2][2][16][2];   // [it][tile][l15][m,l] (jh=1 partials)
    __shared__ float acc_lds[2][64][16];    // [it][lane][16]      (jh=1 partials)

    int bid = blockIdx.x;
    int b = (bid & 7) * 128 + (bid >> 3);   // XCD-chunked
    int g   = b >> 6;
    int rem = b & 63;
    int h   = rem >> 3;
    int iq  = rem & 7;
    int wv   = threadIdx.x >> 6;
    int lane = threadIdx.x & 63;
    int it = wv & 1, jh = wv >> 1;
    int l15 = lane & 15, quad = lane >> 4;
    int ibw = iq * 64 + it * 32;
    const float scale2 = 0.17677669529663687f * 1.4426950408889634f;
    const float LOG2E  = 1.4426950408889634f;

    for (int idx = threadIdx.x; idx < 512; idx += 256)
        bias_lds[idx] = dist_bias[idx * 8 + h] * LOG2E;
    __syncthreads();
    int cnt = counts[g];

    size_t qoff = ((size_t)(g * 512 + ibw + l15)) * 256 + h * 32 + quad * 8;
    short8v qfh0 = *(const short8v*)(qh  + qoff);
    short8v qfl0 = *(const short8v*)(qlo + qoff);
    short8v qfh1 = *(const short8v*)(qh  + qoff + 16 * 256);
    short8v qfl1 = *(const short8v*)(qlo + qoff + 16 * 256);

    float m0s = -INFINITY, l0s = 0.f, m1s = -INFINITY, l1s = 0.f;
    f32x4 t0a0 = {0.f,0.f,0.f,0.f}, t0a1 = {0.f,0.f,0.f,0.f};
    f32x4 t1a0 = {0.f,0.f,0.f,0.f}, t1a1 = {0.f,0.f,0.f,0.f};

    const ushort* vbase = vt + ((size_t)((g * 8 + h) * 32)) * 512;
    const ushort* dR0 = dbuf + ((size_t)(g * 512 + ibw + l15)) * 512;
    const ushort* dR1 = dR0 + (size_t)16 * 512;
    size_t krowb = (size_t)(g * 512);

    auto tile_step = [&](int jb, const ushort* dRow, bool full,
                         short8v qfh, short8v qfl,
                         float& m, float& lsum, f32x4& a0, f32x4& a1,
                         short8v kfh0, short8v kfl0, short8v kfh1, short8v kfl1,
                         half8v v0, half8v v1) {
        float p[8];
        f32x4 c0 = {0.f,0.f,0.f,0.f};
        c0 = __builtin_amdgcn_mfma_f32_16x16x32_bf16(kfl0, qfh, c0, 0, 0, 0);
        c0 = __builtin_amdgcn_mfma_f32_16x16x32_bf16(kfh0, qfl, c0, 0, 0, 0);
        c0 = __builtin_amdgcn_mfma_f32_16x16x32_bf16(kfh0, qfh, c0, 0, 0, 0);
        f32x4 c1 = {0.f,0.f,0.f,0.f};
        c1 = __builtin_amdgcn_mfma_f32_16x16x32_bf16(kfl1, qfh, c1, 0, 0, 0);
        c1 = __builtin_amdgcn_mfma_f32_16x16x32_bf16(kfh1, qfl, c1, 0, 0, 0);
        c1 = __builtin_amdgcn_mfma_f32_16x16x32_bf16(kfh1, qfh, c1, 0, 0, 0);
        ushort4 d0 = *(const ushort4*)(dRow + jb + quad * 4);
        ushort4 d1 = *(const ushort4*)(dRow + jb + 16 + quad * 4);
        const ushort* dr0 = (const ushort*)&d0;
        const ushort* dr1 = (const ushort*)&d1;
        if (full) {
#pragma unroll
            for (int r = 0; r < 4; ++r) p[r]     = c0[r] * scale2 + bias_lds[dr0[r]];
#pragma unroll
            for (int r = 0; r < 4; ++r) p[4 + r] = c1[r] * scale2 + bias_lds[dr1[r]];
        } else {
#pragma unroll
            for (int r = 0; r < 4; ++r) {
                float s = c0[r] * scale2 + bias_lds[dr0[r]];
                p[r] = ((jb + quad * 4 + r) < cnt) ? s : -1e30f;
            }
#pragma unroll
            for (int r = 0; r < 4; ++r) {
                float s = c1[r] * scale2 + bias_lds[dr1[r]];
                p[4 + r] = ((jb + 16 + quad * 4 + r) < cnt) ? s : -1e30f;
            }
        }
        float mx = fmaxf(fmaxf(fmaxf(p[0], p[1]), fmaxf(p[2], p[3])),
                         fmaxf(fmaxf(p[4], p[5]), fmaxf(p[6], p[7])));
        mx = fmaxf(mx, __shfl_xor(mx, 16));
        mx = fmaxf(mx, __shfl_xor(mx, 32));
        float mnew = fmaxf(m, mx);
        float corr = exp2f(m - mnew);
        m = mnew;
        float m10 = m - 10.f;    // P scaled by 2^10: fp16 weights stay normal
        if (full) {
#pragma unroll
            for (int u = 0; u < 8; ++u) p[u] = exp2f(p[u] - m10);
        } else {
#pragma unroll
            for (int u = 0; u < 8; ++u)
                p[u] = (p[u] > -1e29f) ? exp2f(p[u] - m10) : 0.f;
        }
        float psum = ((p[0] + p[1]) + (p[2] + p[3])) + ((p[4] + p[5]) + (p[6] + p[7]));
        psum += __shfl_xor(psum, 16);
        psum += __shfl_xor(psum, 32);
        lsum = lsum * corr + psum;
#pragma unroll
        for (int r = 0; r < 4; ++r) {
            float cr = __shfl(corr, quad * 4 + r);
            a0[r] *= cr; a1[r] *= cr;
        }
        unsigned pk0A = pack_h2(p[0], p[1]), pk1A = pack_h2(p[2], p[3]);
        unsigned pk0B = pack_h2(p[4], p[5]), pk1B = pack_h2(p[6], p[7]);
        int srcA = l15 + 16 * (2 * (quad & 1));
        int srcB = srcA + 16;
        unsigned w0A = __shfl((int)pk0A, srcA), w1A = __shfl((int)pk1A, srcA);
        unsigned w2A = __shfl((int)pk0A, srcB), w3A = __shfl((int)pk1A, srcB);
        unsigned w0B = __shfl((int)pk0B, srcA), w1B = __shfl((int)pk1B, srcA);
        unsigned w2B = __shfl((int)pk0B, srcB), w3B = __shfl((int)pk1B, srcB);
        bool hiT = (quad >= 2);
        union { unsigned u[4]; half8v hh; } pu;
        pu.u[0] = hiT ? w0B : w0A;
        pu.u[1] = hiT ? w1B : w1A;
        pu.u[2] = hiT ? w2B : w2A;
        pu.u[3] = hiT ? w3B : w3A;
        half8v pa = pu.hh;
        a0 = __builtin_amdgcn_mfma_f32_16x16x32_f16(pa, v0, a0, 0, 0, 0);
        a1 = __builtin_amdgcn_mfma_f32_16x16x32_f16(pa, v1, a1, 0, 0, 0);
    };

    int jlo = jh * 256, jhi = jlo + 256;
    for (int jb = jlo; jb < jhi; jb += 32) {
        bool full = (jb + 32 <= cnt);
        size_t koff = (krowb + jb + l15) * 256 + h * 32 + quad * 8;
        short8v kfh0 = *(const short8v*)(kh  + koff);
        short8v kfl0 = *(const short8v*)(klo + koff);
        short8v kfh1 = *(const short8v*)(kh  + koff + 16 * 256);
        short8v kfl1 = *(const short8v*)(klo + koff + 16 * 256);
        half8v v0 = *(const half8v*)(vbase + (size_t)l15 * 512 + jb + quad * 8);
        half8v v1 = *(const half8v*)(vbase + (size_t)(l15 + 16) * 512 + jb + quad * 8);
        tile_step(jb, dR0, full, qfh0, qfl0, m0s, l0s, t0a0, t0a1,
                  kfh0, kfl0, kfh1, kfl1, v0, v1);
        tile_step(jb, dR1, full, qfh1, qfl1, m1s, l1s, t1a0, t1a1,
                  kfh0, kfl0, kfh1, kfl1, v0, v1);
    }

    // ---- merge the two j-half partials (flash combine), jh0 owns the result ----
    if (jh == 1) {
        if (quad == 0) {
            ml_lds[it][0][l15][0] = m0s; ml_lds[it][0][l15][1] = l0s;
            ml_lds[it][1][l15][0] = m1s; ml_lds[it][1][l15][1] = l1s;
        }
        float* ap = &acc_lds[it][lane][0];
#pragma unroll
        for (int r = 0; r < 4; ++r) {
            ap[r]      = t0a0[r];
            ap[4 + r]  = t0a1[r];
            ap[8 + r]  = t1a0[r];
            ap[12 + r] = t1a1[r];
        }
    }
    __syncthreads();
    if (jh == 0) {
        float mp0 = ml_lds[it][0][l15][0], lp0 = ml_lds[it][0][l15][1];
        float mp1 = ml_lds[it][1][l15][0], lp1 = ml_lds[it][1][l15][1];
        float mt0 = fmaxf(m0s, mp0), mt1 = fmaxf(m1s, mp1);
        float ss0 = exp2f(m0s - mt0), sp0 = exp2f(mp0 - mt0);
        float ss1 = exp2f(m1s - mt1), sp1 = exp2f(mp1 - mt1);
        float lt0 = l0s * ss0 + lp0 * sp0;
        float lt1 = l1s * ss1 + lp1 * sp1;
        float inv0 = lt0 > 0.f ? 1.f / lt0 : 0.f;
        float inv1 = lt1 > 0.f ? 1.f / lt1 : 0.f;
        const float* ap = &acc_lds[it][lane][0];
#pragma unroll
        for (int r = 0; r < 4; ++r) {
            int q4r = quad * 4 + r;
            float a0s = __shfl(ss0, q4r), a0p = __shfl(sp0, q4r), ir0 = __shfl(inv0, q4r);
            float a1s = __shfl(ss1, q4r), a1p = __shfl(sp1, q4r), ir1 = __shfl(inv1, q4r);
            float o00 = (t0a0[r] * a0s + ap[r]      * a0p) * ir0;
            float o01 = (t0a1[r] * a0s + ap[4 + r]  * a0p) * ir0;
            float o10 = (t1a0[r] * a1s + ap[8 + r]  * a1p) * ir1;
            float o11 = (t1a1[r] * a1s + ap[12 + r] * a1p) * ir1;
            size_t row0 = (size_t)(g * 512 + ibw + quad * 4 + r) * 256 + h * 32;
            size_t row1 = row0 + (size_t)16 * 256;
            ushort h00 = f2bf(o00), h01 = f2bf(o01), h10 = f2bf(o10), h11 = f2bf(o11);
            oh_g[row0 + l15]      = h00; ol_g[row0 + l15]      = f2bf(o00 - bf2f(h00));
            oh_g[row0 + 16 + l15] = h01; ol_g[row0 + 16 + l15] = f2bf(o01 - bf2f(h01));
            oh_g[row1 + l15]      = h10; ol_g[row1 + l15]      = f2bf(o10 - bf2f(h10));
            oh_g[row1 + 16 + l15] = h11; ol_g[row1 + 16 + l15] = f2bf(o11 - bf2f(h11));
        }
    }
}

// ---------------- MFMA proj GEMM + bias + ragged unpack + last-graph zeroing ----------------
__global__ __launch_bounds__(256) void k_gemm_proj(
    const ushort* __restrict__ oh, const ushort* __restrict__ ol,
    const ushort* __restrict__ woth, const ushort* __restrict__ wotl,
    const float* __restrict__ bo, const int* __restrict__ starts,
    const int* __restrict__ counts, float* __restrict__ out) {
    int w = threadIdx.x >> 6, lane = threadIdx.x & 63;
    int l15 = lane & 15, quad = lane >> 4;
    int m0 = blockIdx.x * 64 + w * 16;
    int nc0 = blockIdx.y * 64;
    f32x4 acc[4] = {};
    const ushort* ah_p = oh + (size_t)(m0 + l15) * 256 + quad * 8;
    const ushort* al_p = ol + (size_t)(m0 + l15) * 256 + quad * 8;
    for (int kc = 0; kc < 256; kc += 32) {
        short8v ah = *(const short8v*)(ah_p + kc);
        short8v al = *(const short8v*)(al_p + kc);
#pragma unroll
        for (int c = 0; c < 4; ++c) {
            size_t bof = (size_t)(nc0 + c * 16 + l15) * 256 + kc + quad * 8;
            short8v bh = *(const short8v*)(woth + bof);
            short8v bl = *(const short8v*)(wotl + bof);
            acc[c] = __builtin_amdgcn_mfma_f32_16x16x32_bf16(al, bh, acc[c], 0, 0, 0);
            acc[c] = __builtin_amdgcn_mfma_f32_16x16x32_bf16(ah, bl, acc[c], 0, 0, 0);
            acc[c] = __builtin_amdgcn_mfma_f32_16x16x32_bf16(ah, bh, acc[c], 0, 0, 0);
        }
    }
    int g = m0 >> 9;
    int cnt = counts[g], st = starts[g];
    bool lastg = (g == G_ - 1);
    int p0 = (m0 & 511) + quad * 4;
#pragma unroll
    for (int c = 0; c < 4; ++c) {
        int col = nc0 + c * 16 + l15;
        float bias = bo[col];
#pragma unroll
        for (int r = 0; r < 4; ++r) {
            int p = p0 + r;
            if (p < cnt)
                out[(size_t)(st + p) * 256 + col] = lastg ? 0.f : (acc[c][r] + bias);
        }
    }
}

// ---------------- launch ----------------
extern "C" void kernel_launch(void* const* d_in, const int* in_sizes, int n_in,
                              void* d_out, int out_size, void* d_ws, size_t ws_size,
                              hipStream_t stream) {
    const float* node_feature = (const float*)d_in[0];
    const float* edge_feature = (const float*)d_in[1];
    const float* centrality   = (const float*)d_in[2];
    const float* dist_bias    = (const float*)d_in[3];
    const float* Wq           = (const float*)d_in[4];
    const float* Wkv          = (const float*)d_in[5];
    const float* Wo           = (const float*)d_in[6];
    const float* bo           = (const float*)d_in[7];
    const int*   edge_index   = (const int*)d_in[8];
    const int*   batch        = (const int*)d_in[9];
    const int*   dist         = (const int*)d_in[10];
    float* out = (float*)d_out;

    const size_t ND = (size_t)N_ * D_;       // 2M elements
    ushort* xh   = (ushort*)d_ws;            // 16-bit buffers, 4 MB each
    ushort* xl   = xh  + ND;
    ushort* qh   = xl  + ND;
    ushort* qlo  = qh  + ND;
    ushort* kh   = qlo + ND;
    ushort* klo  = kh  + ND;
    ushort* vt   = klo + ND;
    ushort* dbuf = vt  + ND;                 // G*MN*MN ushort (8.4 MB)
    ushort* oh_g = dbuf + (size_t)G_ * MN_ * MN_;
    ushort* ol_g = oh_g + ND;
    ushort* wt_h = ol_g + ND;                // 768*256
    ushort* wt_l = wt_h + (size_t)768 * 256;
    ushort* wot_h= wt_l + (size_t)768 * 256; // 256*256
    ushort* wot_l= wot_h + (size_t)256 * 256;
    int* deg    = (int*)(wot_l + (size_t)256 * 256);
    int* bstart = deg + N_;
    int* counts = bstart + G_;
    int* starts = counts + G_;
    int* offs   = starts + G_;
    int* cursor = offs + N_;
    int* eids   = cursor + N_;

    const int* src = edge_index;  // row 0 of (2, E)

    k_prep0<<<N_ / 256, 256, 0, stream>>>(deg, bstart);
    k_prep1<<<800, 256, 0, stream>>>(src, deg, batch, bstart, Wq, Wkv, Wo,
                                     wt_h, wt_l, wot_h, wot_l);
    k_prep2<<<1, 256, 0, stream>>>(bstart, starts, counts, deg, offs, cursor);
    k_fill_csr<<<E_ / 256, 256, 0, stream>>>(src, cursor, eids);
    k_dist16<<<(G_ * MN_ * MN_) / (256 * 8), 256, 0, stream>>>(dist, dbuf);
    k_build_dense<<<(N_ * 64) / 256, 256, 0, stream>>>(node_feature, centrality, edge_feature,
                                                       deg, offs, eids, batch, starts, xh, xl);
    k_gemm_qkv<<<dim3(64, 12), 256, 0, stream>>>(xh, xl, wt_h, wt_l,
                                                 qh, qlo, kh, klo, vt);
    k_attn2<<<1024, 256, 0, stream>>>(qh, qlo, kh, klo, vt, dbuf, dist_bias,
                                      counts, oh_g, ol_g);
    k_gemm_proj<<<dim3(128, 4), 256, 0, stream>>>(oh_g, ol_g, wot_h, wot_l,
                                                  bo, starts, counts, out);
}

// Round 16
// 139.364 us; speedup vs baseline: 1.2114x; 1.2114x over previous
//
#include <hip/hip_runtime.h>
#include <hip/hip_bf16.h>
#include <math.h>

constexpr int N_   = 8192;
constexpr int D_   = 256;
constexpr int E_   = 131072;
constexpr int G_   = 16;
constexpr int MN_  = 512;
constexpr int H_   = 8;
constexpr int MAXG_= 512;

typedef __attribute__((ext_vector_type(8))) short short8v;      // 8 bf16 (4 VGPR)
typedef _Float16 half8v __attribute__((ext_vector_type(8)));    // 8 fp16 (4 VGPR)
typedef __attribute__((ext_vector_type(4))) float f32x4;        // MFMA C/D

// ---- bf16 helpers (RTNE via integer ops; inputs finite) ----
__device__ inline ushort f2bf(float f) {
    unsigned u = __float_as_uint(f);
    return (ushort)((u + 0x7FFFu + ((u >> 16) & 1u)) >> 16);
}
__device__ inline float bf2f(ushort h) { return __uint_as_float((unsigned)h << 16); }
// ---- fp16 helpers ----
__device__ inline ushort f2h(float f) {
    _Float16 h = (_Float16)f; ushort u; __builtin_memcpy(&u, &h, 2); return u;
}
__device__ inline unsigned pack_h2(float a, float b) {   // low = a, high = b (RTZ, 1 instr)
    auto h = __builtin_amdgcn_cvt_pkrtz(a, b);
    unsigned u; __builtin_memcpy(&u, &h, 4); return u;
}

// ---------------- prep0: zero deg + init bstart ----------------
__global__ void k_prep0(int* __restrict__ deg, int* __restrict__ bstart) {
    int i = blockIdx.x * 256 + threadIdx.x;
    if (i < N_) deg[i] = 0;
    if (i < G_) bstart[i] = -1;
}

// ---------------- weight transpose + hi/lo split (device helper) ----------------
__device__ void wt_dev(const float* __restrict__ W, int ncols,
                       ushort* __restrict__ wth, ushort* __restrict__ wtl,
                       int bx, int by) {
    __shared__ float tile[32][33];
    int c0 = bx * 32, k0 = by * 32;
    int t = threadIdx.x;
    int tr = t >> 5, tc = t & 31;
#pragma unroll
    for (int i = 0; i < 4; ++i)
        tile[tr * 4 + i][tc] = W[(size_t)(k0 + tr * 4 + i) * ncols + c0 + tc];
    __syncthreads();
    int cr = t >> 3, kq = (t & 7) * 4;
    ushort4 hh, ll;
    float v;
    v = tile[kq + 0][cr]; hh.x = f2bf(v); ll.x = f2bf(v - bf2f(hh.x));
    v = tile[kq + 1][cr]; hh.y = f2bf(v); ll.y = f2bf(v - bf2f(hh.y));
    v = tile[kq + 2][cr]; hh.z = f2bf(v); ll.z = f2bf(v - bf2f(hh.z));
    v = tile[kq + 3][cr]; hh.w = f2bf(v); ll.w = f2bf(v - bf2f(hh.w));
    *(ushort4*)(wth + (size_t)(c0 + cr) * 256 + k0 + kq) = hh;
    *(ushort4*)(wtl + (size_t)(c0 + cr) * 256 + k0 + kq) = ll;
}

// ---------------- prep1: deg atomics + batch bounds + 3 weight transposes ----------------
__global__ __launch_bounds__(256) void k_prep1(
    const int* __restrict__ src, int* __restrict__ deg,
    const int* __restrict__ batch, int* __restrict__ bstart,
    const float* __restrict__ Wq, const float* __restrict__ Wkv,
    const float* __restrict__ Wo,
    ushort* __restrict__ wt_h, ushort* __restrict__ wt_l,
    ushort* __restrict__ wot_h, ushort* __restrict__ wot_l) {
    int bid = blockIdx.x;
    if (bid < 512) {
        int e = bid * 256 + threadIdx.x;
        atomicAdd(deg + src[e], 1);
    } else if (bid < 544) {
        int n = (bid - 512) * 256 + threadIdx.x;
        int g = batch[n];
        if (n == 0 || batch[n - 1] != g) bstart[g] = n;
    } else {
        int wid = bid - 544;
        if (wid < 64)        wt_dev(Wq,  256, wt_h, wt_l, wid & 7, wid >> 3);
        else if (wid < 192)  wt_dev(Wkv, 512, wt_h + 256 * 256, wt_l + 256 * 256,
                                    (wid - 64) & 15, (wid - 64) >> 4);
        else                 wt_dev(Wo,  256, wot_h, wot_l, (wid - 192) & 7, (wid - 192) >> 3);
    }
}

// ---------------- prep2: starts/counts backward-fill + exclusive deg scan ----------------
__global__ void k_prep2(const int* __restrict__ bstart, int* __restrict__ starts,
                        int* __restrict__ counts, const int* __restrict__ deg,
                        int* __restrict__ offs, int* __restrict__ cursor) {
    int t = threadIdx.x;
    if (t == 0) {
        int next = N_;
        for (int g = G_ - 1; g >= 0; --g) {
            int b = bstart[g];
            int s = (b >= 0) ? b : next;
            starts[g] = s;
            counts[g] = next - s;
            next = s;
        }
    }
    __shared__ int sums[256];
    int base = t * 32;
    int local[32];
    int s = 0;
#pragma unroll
    for (int k = 0; k < 32; ++k) { local[k] = deg[base + k]; s += local[k]; }
    sums[t] = s;
    __syncthreads();
    for (int off = 1; off < 256; off <<= 1) {
        int v = (t >= off) ? sums[t - off] : 0;
        __syncthreads();
        sums[t] += v;
        __syncthreads();
    }
    int acc = sums[t] - s;
#pragma unroll
    for (int k = 0; k < 32; ++k) {
        offs[base + k] = acc;
        cursor[base + k] = acc;
        acc += local[k];
    }
}

__global__ void k_fill_csr(const int* __restrict__ src, int* __restrict__ cursor,
                           int* __restrict__ eids) {
    int e = blockIdx.x * 256 + threadIdx.x;
    if (e < E_) {
        int slot = atomicAdd(cursor + src[e], 1);
        eids[slot] = e;
    }
}

// ---------------- build dense batch (CSR gather, 4-way unrolled), emit bf16 hi/lo ----------------
__global__ void k_build_dense(const float* __restrict__ nf, const float* __restrict__ cent,
                              const float* __restrict__ ef, const int* __restrict__ deg,
                              const int* __restrict__ offs, const int* __restrict__ eids,
                              const int* __restrict__ batch, const int* __restrict__ starts,
                              ushort* __restrict__ xh, ushort* __restrict__ xl) {
    int t  = blockIdx.x * 256 + threadIdx.x;
    int n  = t >> 6;
    int c4 = (t & 63) * 4;
    if (n >= N_) return;
    int g = batch[n];
    int p = n - starts[g];
    if (p >= MN_) return;
    int row = g * MN_ + p;
    int dn = deg[n];
    int dg = min(dn, MAXG_ - 1);
    float4 a = *(const float4*)(nf   + (size_t)n  * D_ + c4);
    float4 b = *(const float4*)(cent + (size_t)dg * D_ + c4);
    float4 o;
    o.x = a.x + b.x; o.y = a.y + b.y; o.z = a.z + b.z; o.w = a.w + b.w;
    int beg = offs[n], end = beg + dn;
    int idx = beg;
    for (; idx + 4 <= end; idx += 4) {
        int e0 = eids[idx], e1 = eids[idx + 1], e2 = eids[idx + 2], e3 = eids[idx + 3];
        float4 v0 = *(const float4*)(ef + (size_t)e0 * D_ + c4);
        float4 v1 = *(const float4*)(ef + (size_t)e1 * D_ + c4);
        float4 v2 = *(const float4*)(ef + (size_t)e2 * D_ + c4);
        float4 v3 = *(const float4*)(ef + (size_t)e3 * D_ + c4);
        o.x += v0.x; o.y += v0.y; o.z += v0.z; o.w += v0.w;
        o.x += v1.x; o.y += v1.y; o.z += v1.z; o.w += v1.w;
        o.x += v2.x; o.y += v2.y; o.z += v2.z; o.w += v2.w;
        o.x += v3.x; o.y += v3.y; o.z += v3.z; o.w += v3.w;
    }
    for (; idx < end; ++idx) {
        int e = eids[idx];
        float4 v = *(const float4*)(ef + (size_t)e * D_ + c4);
        o.x += v.x; o.y += v.y; o.z += v.z; o.w += v.w;
    }
    ushort4 hh, ll;
    hh.x = f2bf(o.x); ll.x = f2bf(o.x - bf2f(hh.x));
    hh.y = f2bf(o.y); ll.y = f2bf(o.y - bf2f(hh.y));
    hh.z = f2bf(o.z); ll.z = f2bf(o.z - bf2f(hh.z));
    hh.w = f2bf(o.w); ll.w = f2bf(o.w - bf2f(hh.w));
    *(ushort4*)(xh + (size_t)row * D_ + c4) = hh;
    *(ushort4*)(xl + (size_t)row * D_ + c4) = ll;
}

// ---------------- MFMA QKV GEMM: 2 row-tiles/wave; V emitted as fp16 ----------------
__global__ __launch_bounds__(256) void k_gemm_qkv(
    const ushort* __restrict__ xh, const ushort* __restrict__ xl,
    const ushort* __restrict__ wth, const ushort* __restrict__ wtl,
    ushort* __restrict__ qh, ushort* __restrict__ qlo,
    ushort* __restrict__ kh, ushort* __restrict__ klo,
    ushort* __restrict__ vt) {
    int w = threadIdx.x >> 6, lane = threadIdx.x & 63;
    int l15 = lane & 15, quad = lane >> 4;
    int m0 = blockIdx.x * 128 + w * 32;
    int nc0 = blockIdx.y * 64;
    f32x4 acc[2][4] = {};
    const ushort* a0h = xh + (size_t)(m0 + l15) * 256 + quad * 8;
    const ushort* a0l = xl + (size_t)(m0 + l15) * 256 + quad * 8;
    for (int kc = 0; kc < 256; kc += 32) {
        short8v ah0 = *(const short8v*)(a0h + kc);
        short8v al0 = *(const short8v*)(a0l + kc);
        short8v ah1 = *(const short8v*)(a0h + 16 * 256 + kc);
        short8v al1 = *(const short8v*)(a0l + 16 * 256 + kc);
#pragma unroll
        for (int c = 0; c < 4; ++c) {
            size_t bo = (size_t)(nc0 + c * 16 + l15) * 256 + kc + quad * 8;
            short8v bh = *(const short8v*)(wth + bo);
            short8v bl = *(const short8v*)(wtl + bo);
            acc[0][c] = __builtin_amdgcn_mfma_f32_16x16x32_bf16(al0, bh, acc[0][c], 0, 0, 0);
            acc[0][c] = __builtin_amdgcn_mfma_f32_16x16x32_bf16(ah0, bl, acc[0][c], 0, 0, 0);
            acc[0][c] = __builtin_amdgcn_mfma_f32_16x16x32_bf16(ah0, bh, acc[0][c], 0, 0, 0);
            acc[1][c] = __builtin_amdgcn_mfma_f32_16x16x32_bf16(al1, bh, acc[1][c], 0, 0, 0);
            acc[1][c] = __builtin_amdgcn_mfma_f32_16x16x32_bf16(ah1, bl, acc[1][c], 0, 0, 0);
            acc[1][c] = __builtin_amdgcn_mfma_f32_16x16x32_bf16(ah1, bh, acc[1][c], 0, 0, 0);
        }
    }
    int seg = nc0 >> 8;          // 0:Q 1:K 2:V
#pragma unroll
    for (int t = 0; t < 2; ++t) {
        int m0t = m0 + t * 16;
        int g = m0t >> 9;
        int r0 = m0t + quad * 4;
#pragma unroll
        for (int c = 0; c < 4; ++c) {
            int col = nc0 + c * 16 + l15;
            if (seg == 0) {
#pragma unroll
                for (int r = 0; r < 4; ++r) {
                    float v = acc[t][c][r];
                    ushort hh = f2bf(v);
                    qh [(size_t)(r0 + r) * 256 + col] = hh;
                    qlo[(size_t)(r0 + r) * 256 + col] = f2bf(v - bf2f(hh));
                }
            } else if (seg == 1) {
                int cc = col - 256;
#pragma unroll
                for (int r = 0; r < 4; ++r) {
                    float v = acc[t][c][r];
                    ushort hh = f2bf(v);
                    kh [(size_t)(r0 + r) * 256 + cc] = hh;
                    klo[(size_t)(r0 + r) * 256 + cc] = f2bf(v - bf2f(hh));
                }
            } else {
                int cv = col - 512;
                int h = cv >> 5, d = cv & 31;
                int j0 = (m0t & 511) + quad * 4;
                ushort4 vv;
                vv.x = f2h(acc[t][c][0]); vv.y = f2h(acc[t][c][1]);
                vv.z = f2h(acc[t][c][2]); vv.w = f2h(acc[t][c][3]);
                *(ushort4*)(vt + ((size_t)((g * 8 + h) * 32 + d)) * 512 + j0) = vv;
            }
        }
    }
}

// ---------------- fused MFMA attention (software-pipelined j-loop) + proj ----------------
__global__ __launch_bounds__(512) void k_attn_fused(
    const ushort* __restrict__ qh, const ushort* __restrict__ qlo,
    const ushort* __restrict__ kh, const ushort* __restrict__ klo,
    const ushort* __restrict__ vt,
    const int* __restrict__ dist, const float* __restrict__ dist_bias,
    const int* __restrict__ starts, const int* __restrict__ counts,
    const ushort* __restrict__ woth, const ushort* __restrict__ wotl,
    const float* __restrict__ bo, float* __restrict__ out)
{
    __shared__ ushort dist_lds[32][272];   // 17.4 KB; reused as O-hi after attn
    __shared__ ushort olo_lds[32][264];    // 16.9 KB (O-lo)
    __shared__ float  biasH[8][516];       // 16.5 KB, pre-scaled by log2(e)

    int bid = blockIdx.x;
    int b = (bid & 7) * 32 + (bid >> 3);   // XCD-chunked: 2 graphs per XCD
    int g  = b >> 4;
    int ib = (b & 15) * 32;
    int w    = threadIdx.x >> 6;           // = head
    int lane = threadIdx.x & 63;
    int l15  = lane & 15, quad = lane >> 4;
    int h = w;
    const float scale2 = 0.17677669529663687f * 1.4426950408889634f;
    const float LOG2E  = 1.4426950408889634f;

    for (int idx = threadIdx.x; idx < 4096; idx += 512)
        biasH[idx & 7][idx >> 3] = dist_bias[idx] * LOG2E;
    {   // stage 32 dist rows as clipped ushort
        int r = threadIdx.x >> 4;             // 0..31
        int c0 = (threadIdx.x & 15) * 32;
        const int* drow = dist + ((size_t)(g * 512 + ib + r)) * 512 + c0;
#pragma unroll
        for (int u = 0; u < 32; u += 8) {
            int4 da = *(const int4*)(drow + u);
            int4 db = *(const int4*)(drow + u + 4);
            ushort4 s0, s1;
            s0.x = (ushort)min(da.x, 511); s0.y = (ushort)min(da.y, 511);
            s0.z = (ushort)min(da.z, 511); s0.w = (ushort)min(da.w, 511);
            s1.x = (ushort)min(db.x, 511); s1.y = (ushort)min(db.y, 511);
            s1.z = (ushort)min(db.z, 511); s1.w = (ushort)min(db.w, 511);
            *(ushort4*)&dist_lds[r][c0 + u]     = s0;
            *(ushort4*)&dist_lds[r][c0 + u + 4] = s1;
        }
    }
    __syncthreads();
    int cnt = counts[g];

    size_t qoff = ((size_t)(g * 512 + ib + l15)) * 256 + h * 32 + quad * 8;
    short8v qfh0 = *(const short8v*)(qh  + qoff);
    short8v qfl0 = *(const short8v*)(qlo + qoff);
    short8v qfh1 = *(const short8v*)(qh  + qoff + 16 * 256);
    short8v qfl1 = *(const short8v*)(qlo + qoff + 16 * 256);

    float m0s = -INFINITY, l0s = 0.f, m1s = -INFINITY, l1s = 0.f;
    f32x4 t0a0 = {0.f,0.f,0.f,0.f}, t0a1 = {0.f,0.f,0.f,0.f};
    f32x4 t1a0 = {0.f,0.f,0.f,0.f}, t1a1 = {0.f,0.f,0.f,0.f};

    const ushort* vbase = vt + ((size_t)((g * 8 + h) * 32)) * 512;
    size_t krowb = (size_t)(g * 512);

    // softmax+PV for one i-tile, QK^T results already in c0/c1 (math identical to r14)
    auto softmax_pv = [&](int jb, int rowoff, bool full, f32x4 c0, f32x4 c1,
                          float& m, float& lsum, f32x4& a0, f32x4& a1,
                          half8v v0, half8v v1) {
        float p[8];
        ushort4 d0 = *(const ushort4*)&dist_lds[rowoff + l15][jb + quad * 4];
        ushort4 d1 = *(const ushort4*)&dist_lds[rowoff + l15][jb + 16 + quad * 4];
        const ushort* dr0 = (const ushort*)&d0;
        const ushort* dr1 = (const ushort*)&d1;
        if (full) {       // uniform branch: bit-exact with masked path
#pragma unroll
            for (int r = 0; r < 4; ++r) p[r]     = c0[r] * scale2 + biasH[h][dr0[r]];
#pragma unroll
            for (int r = 0; r < 4; ++r) p[4 + r] = c1[r] * scale2 + biasH[h][dr1[r]];
        } else {
#pragma unroll
            for (int r = 0; r < 4; ++r) {
                float s = c0[r] * scale2 + biasH[h][dr0[r]];
                p[r] = ((jb + quad * 4 + r) < cnt) ? s : -1e30f;
            }
#pragma unroll
            for (int r = 0; r < 4; ++r) {
                float s = c1[r] * scale2 + biasH[h][dr1[r]];
                p[4 + r] = ((jb + 16 + quad * 4 + r) < cnt) ? s : -1e30f;
            }
        }
        float mx = fmaxf(fmaxf(fmaxf(p[0], p[1]), fmaxf(p[2], p[3])),
                         fmaxf(fmaxf(p[4], p[5]), fmaxf(p[6], p[7])));
        mx = fmaxf(mx, __shfl_xor(mx, 16));
        mx = fmaxf(mx, __shfl_xor(mx, 32));
        float mnew = fmaxf(m, mx);
        float corr = exp2f(m - mnew);
        m = mnew;
        float m10 = m - 10.f;    // P scaled by 2^10: fp16 weights stay normal
        if (full) {
#pragma unroll
            for (int u = 0; u < 8; ++u) p[u] = exp2f(p[u] - m10);
        } else {
#pragma unroll
            for (int u = 0; u < 8; ++u)
                p[u] = (p[u] > -1e29f) ? exp2f(p[u] - m10) : 0.f;
        }
        float psum = ((p[0] + p[1]) + (p[2] + p[3])) + ((p[4] + p[5]) + (p[6] + p[7]));
        psum += __shfl_xor(psum, 16);
        psum += __shfl_xor(psum, 32);
        lsum = lsum * corr + psum;
#pragma unroll
        for (int r = 0; r < 4; ++r) {
            float cr = __shfl(corr, quad * 4 + r);
            a0[r] *= cr; a1[r] *= cr;
        }
        unsigned pk0A = pack_h2(p[0], p[1]), pk1A = pack_h2(p[2], p[3]);
        unsigned pk0B = pack_h2(p[4], p[5]), pk1B = pack_h2(p[6], p[7]);
        int srcA = l15 + 16 * (2 * (quad & 1));
        int srcB = srcA + 16;
        unsigned w0A = __shfl((int)pk0A, srcA), w1A = __shfl((int)pk1A, srcA);
        unsigned w2A = __shfl((int)pk0A, srcB), w3A = __shfl((int)pk1A, srcB);
        unsigned w0B = __shfl((int)pk0B, srcA), w1B = __shfl((int)pk1B, srcA);
        unsigned w2B = __shfl((int)pk0B, srcB), w3B = __shfl((int)pk1B, srcB);
        bool hiT = (quad >= 2);
        union { unsigned u[4]; half8v hh; } pu;
        pu.u[0] = hiT ? w0B : w0A;
        pu.u[1] = hiT ? w1B : w1A;
        pu.u[2] = hiT ? w2B : w2A;
        pu.u[3] = hiT ? w3B : w3A;
        half8v pa = pu.hh;
        a0 = __builtin_amdgcn_mfma_f32_16x16x32_f16(pa, v0, a0, 0, 0, 0);
        a1 = __builtin_amdgcn_mfma_f32_16x16x32_f16(pa, v1, a1, 0, 0, 0);
    };

    // ---- prologue: K/V for jb=0 ----
    size_t koff0 = (krowb + l15) * 256 + h * 32 + quad * 8;
    short8v kfh0 = *(const short8v*)(kh  + koff0);
    short8v kfl0 = *(const short8v*)(klo + koff0);
    short8v kfh1 = *(const short8v*)(kh  + koff0 + 16 * 256);
    short8v kfl1 = *(const short8v*)(klo + koff0 + 16 * 256);
    half8v v0 = *(const half8v*)(vbase + (size_t)l15 * 512 + quad * 8);
    half8v v1 = *(const half8v*)(vbase + (size_t)(l15 + 16) * 512 + quad * 8);

    for (int jb = 0; jb < 512; jb += 32) {
        bool full = (jb + 32 <= cnt);
        // ---- QK^T for BOTH i-tiles up front (independent of softmax state) ----
        f32x4 c00 = {0.f,0.f,0.f,0.f}, c01 = {0.f,0.f,0.f,0.f};
        f32x4 c10 = {0.f,0.f,0.f,0.f}, c11 = {0.f,0.f,0.f,0.f};
        c00 = __builtin_amdgcn_mfma_f32_16x16x32_bf16(kfl0, qfh0, c00, 0, 0, 0);
        c00 = __builtin_amdgcn_mfma_f32_16x16x32_bf16(kfh0, qfl0, c00, 0, 0, 0);
        c00 = __builtin_amdgcn_mfma_f32_16x16x32_bf16(kfh0, qfh0, c00, 0, 0, 0);
        c01 = __builtin_amdgcn_mfma_f32_16x16x32_bf16(kfl1, qfh0, c01, 0, 0, 0);
        c01 = __builtin_amdgcn_mfma_f32_16x16x32_bf16(kfh1, qfl0, c01, 0, 0, 0);
        c01 = __builtin_amdgcn_mfma_f32_16x16x32_bf16(kfh1, qfh0, c01, 0, 0, 0);
        c10 = __builtin_amdgcn_mfma_f32_16x16x32_bf16(kfl0, qfh1, c10, 0, 0, 0);
        c10 = __builtin_amdgcn_mfma_f32_16x16x32_bf16(kfh0, qfl1, c10, 0, 0, 0);
        c10 = __builtin_amdgcn_mfma_f32_16x16x32_bf16(kfh0, qfh1, c10, 0, 0, 0);
        c11 = __builtin_amdgcn_mfma_f32_16x16x32_bf16(kfl1, qfh1, c11, 0, 0, 0);
        c11 = __builtin_amdgcn_mfma_f32_16x16x32_bf16(kfh1, qfl1, c11, 0, 0, 0);
        c11 = __builtin_amdgcn_mfma_f32_16x16x32_bf16(kfh1, qfh1, c11, 0, 0, 0);
        // save current V, then prefetch next tile's K/V (hidden under softmax chains)
        half8v v0c = v0, v1c = v1;
        if (jb + 32 < 512) {
            size_t koff = (krowb + jb + 32 + l15) * 256 + h * 32 + quad * 8;
            kfh0 = *(const short8v*)(kh  + koff);
            kfl0 = *(const short8v*)(klo + koff);
            kfh1 = *(const short8v*)(kh  + koff + 16 * 256);
            kfl1 = *(const short8v*)(klo + koff + 16 * 256);
            v0 = *(const half8v*)(vbase + (size_t)l15 * 512 + jb + 32 + quad * 8);
            v1 = *(const half8v*)(vbase + (size_t)(l15 + 16) * 512 + jb + 32 + quad * 8);
        }
        // ---- two independent softmax->PV chains ----
        softmax_pv(jb, 0,  full, c00, c01, m0s, l0s, t0a0, t0a1, v0c, v1c);
        softmax_pv(jb, 16, full, c10, c11, m1s, l1s, t1a0, t1a1, v0c, v1c);
    }
    float inv0 = l0s > 0.f ? 1.f / l0s : 0.f;
    float inv1 = l1s > 0.f ? 1.f / l1s : 0.f;

    // ---- stage O (bf16 hi/lo); dist region retires to O-hi ----
    __syncthreads();
    ushort* oh_lds = &dist_lds[0][0];      // reused, stride 264
    ushort* ol_lds = &olo_lds[0][0];
#pragma unroll
    for (int r = 0; r < 4; ++r) {
        float ir0 = __shfl(inv0, quad * 4 + r);
        float ir1 = __shfl(inv1, quad * 4 + r);
        int i0 = quad * 4 + r;
        int i1 = 16 + quad * 4 + r;
        float o00 = t0a0[r] * ir0, o01 = t0a1[r] * ir0;
        float o10 = t1a0[r] * ir1, o11 = t1a1[r] * ir1;
        ushort h00 = f2bf(o00), h01 = f2bf(o01), h10 = f2bf(o10), h11 = f2bf(o11);
        oh_lds[i0 * 264 + h * 32 + l15]      = h00;
        ol_lds[i0 * 264 + h * 32 + l15]      = f2bf(o00 - bf2f(h00));
        oh_lds[i0 * 264 + h * 32 + 16 + l15] = h01;
        ol_lds[i0 * 264 + h * 32 + 16 + l15] = f2bf(o01 - bf2f(h01));
        oh_lds[i1 * 264 + h * 32 + l15]      = h10;
        ol_lds[i1 * 264 + h * 32 + l15]      = f2bf(o10 - bf2f(h10));
        oh_lds[i1 * 264 + h * 32 + 16 + l15] = h11;
        ol_lds[i1 * 264 + h * 32 + 16 + l15] = f2bf(o11 - bf2f(h11));
    }
    __syncthreads();

    // ---- in-block projection: wave w -> cols [w*32, w*32+32), 32 rows ----
    f32x4 pacc[2][2] = {};
    for (int kc = 0; kc < 256; kc += 32) {
        short8v ah0 = *(const short8v*)(oh_lds + l15 * 264 + kc + quad * 8);
        short8v al0 = *(const short8v*)(ol_lds + l15 * 264 + kc + quad * 8);
        short8v ah1 = *(const short8v*)(oh_lds + (l15 + 16) * 264 + kc + quad * 8);
        short8v al1 = *(const short8v*)(ol_lds + (l15 + 16) * 264 + kc + quad * 8);
#pragma unroll
        for (int cc = 0; cc < 2; ++cc) {
            int col = w * 32 + cc * 16 + l15;
            size_t bof = (size_t)col * 256 + kc + quad * 8;
            short8v bh = *(const short8v*)(woth + bof);
            short8v bl = *(const short8v*)(wotl + bof);
            pacc[0][cc] = __builtin_amdgcn_mfma_f32_16x16x32_bf16(al0, bh, pacc[0][cc], 0, 0, 0);
            pacc[0][cc] = __builtin_amdgcn_mfma_f32_16x16x32_bf16(ah0, bl, pacc[0][cc], 0, 0, 0);
            pacc[0][cc] = __builtin_amdgcn_mfma_f32_16x16x32_bf16(ah0, bh, pacc[0][cc], 0, 0, 0);
            pacc[1][cc] = __builtin_amdgcn_mfma_f32_16x16x32_bf16(al1, bh, pacc[1][cc], 0, 0, 0);
            pacc[1][cc] = __builtin_amdgcn_mfma_f32_16x16x32_bf16(ah1, bl, pacc[1][cc], 0, 0, 0);
            pacc[1][cc] = __builtin_amdgcn_mfma_f32_16x16x32_bf16(ah1, bh, pacc[1][cc], 0, 0, 0);
        }
    }
    int st = starts[g];
    bool lastg = (g == G_ - 1);
#pragma unroll
    for (int rg = 0; rg < 2; ++rg) {
#pragma unroll
        for (int cc = 0; cc < 2; ++cc) {
            int col = w * 32 + cc * 16 + l15;
            float bias = bo[col];
#pragma unroll
            for (int r = 0; r < 4; ++r) {
                int prow = ib + rg * 16 + quad * 4 + r;
                if (prow < cnt)
                    out[(size_t)(st + prow) * 256 + col] = lastg ? 0.f : (pacc[rg][cc][r] + bias);
            }
        }
    }
}

// ---------------- launch ----------------
extern "C" void kernel_launch(void* const* d_in, const int* in_sizes, int n_in,
                              void* d_out, int out_size, void* d_ws, size_t ws_size,
                              hipStream_t stream) {
    const float* node_feature = (const float*)d_in[0];
    const float* edge_feature = (const float*)d_in[1];
    const float* centrality   = (const float*)d_in[2];
    const float* dist_bias    = (const float*)d_in[3];
    const float* Wq           = (const float*)d_in[4];
    const float* Wkv          = (const float*)d_in[5];
    const float* Wo           = (const float*)d_in[6];
    const float* bo           = (const float*)d_in[7];
    const int*   edge_index   = (const int*)d_in[8];
    const int*   batch        = (const int*)d_in[9];
    const int*   dist         = (const int*)d_in[10];
    float* out = (float*)d_out;

    const size_t ND = (size_t)N_ * D_;       // 2M elements
    ushort* xh   = (ushort*)d_ws;            // 16-bit buffers, 4 MB each
    ushort* xl   = xh  + ND;
    ushort* qh   = xl  + ND;
    ushort* qlo  = qh  + ND;
    ushort* kh   = qlo + ND;
    ushort* klo  = kh  + ND;
    ushort* vt   = klo + ND;
    ushort* wt_h = vt  + ND;                 // 768*256
    ushort* wt_l = wt_h + (size_t)768 * 256;
    ushort* wot_h= wt_l + (size_t)768 * 256; // 256*256
    ushort* wot_l= wot_h + (size_t)256 * 256;
    int* deg    = (int*)(wot_l + (size_t)256 * 256);
    int* bstart = deg + N_;
    int* counts = bstart + G_;
    int* starts = counts + G_;
    int* offs   = starts + G_;
    int* cursor = offs + N_;
    int* eids   = cursor + N_;

    const int* src = edge_index;  // row 0 of (2, E)

    k_prep0<<<N_ / 256, 256, 0, stream>>>(deg, bstart);
    k_prep1<<<800, 256, 0, stream>>>(src, deg, batch, bstart, Wq, Wkv, Wo,
                                     wt_h, wt_l, wot_h, wot_l);
    k_prep2<<<1, 256, 0, stream>>>(bstart, starts, counts, deg, offs, cursor);
    k_fill_csr<<<E_ / 256, 256, 0, stream>>>(src, cursor, eids);
    k_build_dense<<<(N_ * 64) / 256, 256, 0, stream>>>(node_feature, centrality, edge_feature,
                                                       deg, offs, eids, batch, starts, xh, xl);
    k_gemm_qkv<<<dim3(64, 12), 256, 0, stream>>>(xh, xl, wt_h, wt_l,
                                                 qh, qlo, kh, klo, vt);
    k_attn_fused<<<256, 512, 0, stream>>>(qh, qlo, kh, klo, vt, dist, dist_bias,
                                          starts, counts, wot_h, wot_l, bo, out);
}